// Round 1
// baseline (328.677 us; speedup 1.0000x reference)
//
#include <hip/hip_runtime.h>

#define LSEQ 4096
#define EMB  1024
#define NH   16
#define HD   64

typedef __attribute__((ext_vector_type(8))) __bf16 bf16x8;
typedef __attribute__((ext_vector_type(4))) float f32x4;
typedef __attribute__((ext_vector_type(8))) unsigned short u16x8;
typedef __attribute__((ext_vector_type(4))) unsigned short u16x4;
typedef __attribute__((ext_vector_type(4))) float f32x4v;

__device__ __forceinline__ unsigned short f2bf(float f) {
    union { float f; unsigned u; } v; v.f = f;
    unsigned r = v.u + 0x7fffu + ((v.u >> 16) & 1u);
    return (unsigned short)(r >> 16);
}

__device__ __forceinline__ f32x4 mfma16(u16x8 a, u16x8 b, f32x4 c) {
    return __builtin_amdgcn_mfma_f32_16x16x32_bf16(
        __builtin_bit_cast(bf16x8, a), __builtin_bit_cast(bf16x8, b), c, 0, 0, 0);
}

// ---------------- fp32 -> bf16 convert ----------------
__global__ __launch_bounds__(256) void cvt_f32_bf16(const float* __restrict__ in,
                                                    unsigned short* __restrict__ out,
                                                    int n4) {
    int i = blockIdx.x * 256 + threadIdx.x;
    if (i >= n4) return;
    f32x4 v = *(const f32x4*)(in + (size_t)i * 4);
    u16x4 o;
    o[0] = f2bf(v[0]); o[1] = f2bf(v[1]); o[2] = f2bf(v[2]); o[3] = f2bf(v[3]);
    *(u16x4*)(out + (size_t)i * 4) = o;
}

// ---------------- QKV GEMM: C[M=L,N=3E] = X[L,E] * Wattn^T, scatter epilogue ----------------
// A,B both [rows][K=1024] row-major bf16. 128x128 tile, BK=32, 4 waves (2x2), 64x64 per wave.
__global__ __launch_bounds__(256) void gemm_qkv(const unsigned short* __restrict__ A,
                                                const unsigned short* __restrict__ B,
                                                unsigned short* __restrict__ Qo,
                                                unsigned short* __restrict__ Ko,
                                                unsigned short* __restrict__ Vto) {
    __shared__ unsigned short As[128 * 32];
    __shared__ unsigned short Bs[128 * 32];
    const int tid = threadIdx.x;
    const int lane = tid & 63;
    const int wv = tid >> 6;
    const int wm = wv >> 1, wn = wv & 1;
    const int li = lane & 15, g = lane >> 4;
    const int m0 = blockIdx.y * 128, n0 = blockIdx.x * 128;
    f32x4 acc[4][4] = {};
    for (int k0 = 0; k0 < EMB; k0 += 32) {
        for (int c = tid; c < 512; c += 256) {
            const int r = c >> 2, cc = (c & 3) * 8;
            *(u16x8*)(As + r * 32 + cc) = *(const u16x8*)(A + (size_t)(m0 + r) * EMB + k0 + cc);
            *(u16x8*)(Bs + r * 32 + cc) = *(const u16x8*)(B + (size_t)(n0 + r) * EMB + k0 + cc);
        }
        __syncthreads();
        u16x8 af[4], bfr[4];
        for (int mb = 0; mb < 4; ++mb)
            af[mb] = *(const u16x8*)(As + (wm * 64 + mb * 16 + li) * 32 + g * 8);
        for (int nb = 0; nb < 4; ++nb)
            bfr[nb] = *(const u16x8*)(Bs + (wn * 64 + nb * 16 + li) * 32 + g * 8);
        for (int mb = 0; mb < 4; ++mb)
            for (int nb = 0; nb < 4; ++nb)
                acc[mb][nb] = mfma16(af[mb], bfr[nb], acc[mb][nb]);
        __syncthreads();
    }
    for (int mb = 0; mb < 4; ++mb) {
        for (int nb = 0; nb < 4; ++nb) {
            for (int r = 0; r < 4; ++r) {
                const int m = m0 + wm * 64 + mb * 16 + g * 4 + r;
                const int n = n0 + wn * 64 + nb * 16 + li;
                const float v = acc[mb][nb][r];
                if (n < EMB) {
                    // Q scaled by 1/sqrt(hd)=0.125, layout [H][L][64]
                    Qo[((size_t)(n >> 6) * LSEQ + m) * HD + (n & 63)] = f2bf(v * 0.125f);
                } else if (n < 2 * EMB) {
                    const int c = n - EMB;
                    Ko[((size_t)(c >> 6) * LSEQ + m) * HD + (c & 63)] = f2bf(v);
                } else {
                    const int c = n - 2 * EMB;
                    // V transposed per head: [H][64(hd)][L]
                    Vto[((size_t)(c >> 6) * HD + (c & 63)) * LSEQ + m] = f2bf(v);
                }
            }
        }
    }
}

// ---------------- flash attention (causal), 64 q-rows/block, 4 waves x 16 rows ----------------
__global__ __launch_bounds__(256) void attn_fwd(const unsigned short* __restrict__ Q,
                                                const unsigned short* __restrict__ K,
                                                const unsigned short* __restrict__ Vt,
                                                unsigned short* __restrict__ Y) {
    __shared__ unsigned short Qs[64][72];
    __shared__ unsigned short Ks[64][72];
    __shared__ unsigned short Vs[64][72];   // V^T tile: [hd][kv]
    __shared__ unsigned short Ps[4][16][72];
    const int h = blockIdx.y, qb = blockIdx.x;
    const int tid = threadIdx.x, lane = tid & 63, w = tid >> 6;
    const int g = lane >> 4, li = lane & 15;
    {
        const int r = tid >> 2, c = (tid & 3) * 16;
        const unsigned short* src = Q + ((size_t)h * LSEQ + qb * 64 + r) * HD + c;
        *(u16x8*)&Qs[r][c]     = *(const u16x8*)src;
        *(u16x8*)&Qs[r][c + 8] = *(const u16x8*)(src + 8);
    }
    __syncthreads();
    u16x8 aq[2];
    aq[0] = *(const u16x8*)&Qs[w * 16 + li][g * 8];
    aq[1] = *(const u16x8*)&Qs[w * 16 + li][32 + g * 8];
    float m_i[4], l_i[4];
    f32x4 accO[4] = {};
    for (int r = 0; r < 4; ++r) { m_i[r] = -1e30f; l_i[r] = 0.f; }

    for (int j = 0; j <= qb; ++j) {
        {
            const int r = tid >> 2, c = (tid & 3) * 16;
            const unsigned short* ksrc = K + ((size_t)h * LSEQ + j * 64 + r) * HD + c;
            *(u16x8*)&Ks[r][c]     = *(const u16x8*)ksrc;
            *(u16x8*)&Ks[r][c + 8] = *(const u16x8*)(ksrc + 8);
            const unsigned short* vsrc = Vt + ((size_t)h * HD + r) * LSEQ + j * 64 + c;
            *(u16x8*)&Vs[r][c]     = *(const u16x8*)vsrc;
            *(u16x8*)&Vs[r][c + 8] = *(const u16x8*)(vsrc + 8);
        }
        __syncthreads();
        f32x4 s[4] = {};
        for (int jb = 0; jb < 4; ++jb) {
            u16x8 bk0 = *(const u16x8*)&Ks[jb * 16 + li][g * 8];
            u16x8 bk1 = *(const u16x8*)&Ks[jb * 16 + li][32 + g * 8];
            s[jb] = mfma16(aq[0], bk0, s[jb]);
            s[jb] = mfma16(aq[1], bk1, s[jb]);
        }
        if (j == qb) {
            for (int jb = 0; jb < 4; ++jb)
                for (int r = 0; r < 4; ++r) {
                    const int colr = jb * 16 + li, rowr = w * 16 + g * 4 + r;
                    if (colr > rowr) s[jb][r] = -1e30f;
                }
        }
        float mt[4], al[4];
        for (int r = 0; r < 4; ++r) {
            float mm = fmaxf(fmaxf(s[0][r], s[1][r]), fmaxf(s[2][r], s[3][r]));
            mm = fmaxf(mm, __shfl_xor(mm, 1));
            mm = fmaxf(mm, __shfl_xor(mm, 2));
            mm = fmaxf(mm, __shfl_xor(mm, 4));
            mm = fmaxf(mm, __shfl_xor(mm, 8));
            mt[r] = mm;
        }
        float p[4][4];
        for (int r = 0; r < 4; ++r) {
            const float mn = fmaxf(m_i[r], mt[r]);
            al[r] = __expf(m_i[r] - mn);
            m_i[r] = mn;
            float sum = 0.f;
            for (int jb = 0; jb < 4; ++jb) {
                const float pv = __expf(s[jb][r] - mn);
                p[jb][r] = pv;
                sum += pv;
            }
            sum += __shfl_xor(sum, 1);
            sum += __shfl_xor(sum, 2);
            sum += __shfl_xor(sum, 4);
            sum += __shfl_xor(sum, 8);
            l_i[r] = l_i[r] * al[r] + sum;
        }
        for (int o = 0; o < 4; ++o)
            for (int r = 0; r < 4; ++r) accO[o][r] *= al[r];
        for (int jb = 0; jb < 4; ++jb)
            for (int r = 0; r < 4; ++r)
                Ps[w][g * 4 + r][jb * 16 + li] = f2bf(p[jb][r]);
        __syncthreads();  // RAW insurance: P written cross-lane, read below
        for (int o = 0; o < 4; ++o) {
            for (int ks = 0; ks < 2; ++ks) {
                u16x8 ap = *(const u16x8*)&Ps[w][li][ks * 32 + g * 8];
                u16x8 bv = *(const u16x8*)&Vs[o * 16 + li][ks * 32 + g * 8];
                accO[o] = mfma16(ap, bv, accO[o]);
            }
        }
        __syncthreads();
    }
    for (int o = 0; o < 4; ++o)
        for (int r = 0; r < 4; ++r) {
            const int row = qb * 64 + w * 16 + g * 4 + r;
            const int col = h * HD + o * 16 + li;
            Y[(size_t)row * EMB + col] = f2bf(accO[o][r] / l_i[r]);
        }
}

// ---------------- proj GEMM: out[L,E] fp32 = Y[L,E] * Wproj^T ----------------
__global__ __launch_bounds__(256) void gemm_proj(const unsigned short* __restrict__ A,
                                                 const unsigned short* __restrict__ B,
                                                 float* __restrict__ C) {
    __shared__ unsigned short As[128 * 32];
    __shared__ unsigned short Bs[128 * 32];
    const int tid = threadIdx.x;
    const int lane = tid & 63;
    const int wv = tid >> 6;
    const int wm = wv >> 1, wn = wv & 1;
    const int li = lane & 15, g = lane >> 4;
    const int m0 = blockIdx.y * 128, n0 = blockIdx.x * 128;
    f32x4 acc[4][4] = {};
    for (int k0 = 0; k0 < EMB; k0 += 32) {
        for (int c = tid; c < 512; c += 256) {
            const int r = c >> 2, cc = (c & 3) * 8;
            *(u16x8*)(As + r * 32 + cc) = *(const u16x8*)(A + (size_t)(m0 + r) * EMB + k0 + cc);
            *(u16x8*)(Bs + r * 32 + cc) = *(const u16x8*)(B + (size_t)(n0 + r) * EMB + k0 + cc);
        }
        __syncthreads();
        u16x8 af[4], bfr[4];
        for (int mb = 0; mb < 4; ++mb)
            af[mb] = *(const u16x8*)(As + (wm * 64 + mb * 16 + li) * 32 + g * 8);
        for (int nb = 0; nb < 4; ++nb)
            bfr[nb] = *(const u16x8*)(Bs + (wn * 64 + nb * 16 + li) * 32 + g * 8);
        for (int mb = 0; mb < 4; ++mb)
            for (int nb = 0; nb < 4; ++nb)
                acc[mb][nb] = mfma16(af[mb], bfr[nb], acc[mb][nb]);
        __syncthreads();
    }
    for (int mb = 0; mb < 4; ++mb)
        for (int nb = 0; nb < 4; ++nb)
            for (int r = 0; r < 4; ++r) {
                const int m = m0 + wm * 64 + mb * 16 + g * 4 + r;
                const int n = n0 + wn * 64 + nb * 16 + li;
                C[(size_t)m * EMB + n] = acc[mb][nb][r];
            }
}

extern "C" void kernel_launch(void* const* d_in, const int* in_sizes, int n_in,
                              void* d_out, int out_size, void* d_ws, size_t ws_size,
                              hipStream_t stream) {
    const float* x      = (const float*)d_in[0];
    const float* w_attn = (const float*)d_in[1];
    const float* w_proj = (const float*)d_in[2];
    float* out = (float*)d_out;

    unsigned short* ws  = (unsigned short*)d_ws;
    unsigned short* xb  = ws;                                  // L*E
    unsigned short* wab = xb + (size_t)LSEQ * EMB;             // 3E*E
    unsigned short* wpb = wab + (size_t)3 * EMB * EMB;         // E*E
    unsigned short* Qb  = wpb + (size_t)EMB * EMB;             // H*L*64 = L*E
    unsigned short* Kb  = Qb + (size_t)LSEQ * EMB;
    unsigned short* Vtb = Kb + (size_t)LSEQ * EMB;
    unsigned short* Yb  = Vtb + (size_t)LSEQ * EMB;            // L*E

    const int nx = LSEQ * EMB / 4, na = 3 * EMB * EMB / 4, np = EMB * EMB / 4;
    cvt_f32_bf16<<<(nx + 255) / 256, 256, 0, stream>>>(x, xb, nx);
    cvt_f32_bf16<<<(na + 255) / 256, 256, 0, stream>>>(w_attn, wab, na);
    cvt_f32_bf16<<<(np + 255) / 256, 256, 0, stream>>>(w_proj, wpb, np);

    gemm_qkv<<<dim3(3 * EMB / 128, LSEQ / 128), 256, 0, stream>>>(xb, wab, Qb, Kb, Vtb);
    attn_fwd<<<dim3(LSEQ / 64, NH), 256, 0, stream>>>(Qb, Kb, Vtb, Yb);
    gemm_proj<<<dim3(EMB / 128, LSEQ / 128), 256, 0, stream>>>(Yb, wpb, out);
}

// Round 2
// 170.668 us; speedup vs baseline: 1.9258x; 1.9258x over previous
//
#include <hip/hip_runtime.h>

#define LSEQ 4096
#define EMB  1024
#define NH   16
#define HD   64

typedef __attribute__((ext_vector_type(8))) __bf16 bf16x8;
typedef __attribute__((ext_vector_type(4))) float f32x4;
typedef __attribute__((ext_vector_type(8))) unsigned short u16x8;
typedef __attribute__((ext_vector_type(4))) unsigned short u16x4;

__device__ __forceinline__ unsigned short f2bf(float f) {
    union { float f; unsigned u; } v; v.f = f;
    unsigned r = v.u + 0x7fffu + ((v.u >> 16) & 1u);
    return (unsigned short)(r >> 16);
}

__device__ __forceinline__ unsigned cvt_pk_bf16(float a, float b) {
    unsigned r;
    asm("v_cvt_pk_bf16_f32 %0, %1, %2" : "=v"(r) : "v"(a), "v"(b));
    return r;
}

__device__ __forceinline__ f32x4 mfma16(u16x8 a, u16x8 b, f32x4 c) {
    return __builtin_amdgcn_mfma_f32_16x16x32_bf16(
        __builtin_bit_cast(bf16x8, a), __builtin_bit_cast(bf16x8, b), c, 0, 0, 0);
}

__device__ __forceinline__ void gload16(const void* g, void* l) {
    __builtin_amdgcn_global_load_lds((const __attribute__((address_space(1))) unsigned int*)g,
                                     (__attribute__((address_space(3))) unsigned int*)l,
                                     16, 0, 0);
}

// ---------------- fp32 -> bf16 convert ----------------
__global__ __launch_bounds__(256) void cvt_f32_bf16(const float* __restrict__ in,
                                                    unsigned short* __restrict__ out,
                                                    int n4) {
    int i = blockIdx.x * 256 + threadIdx.x;
    if (i >= n4) return;
    f32x4 v = *(const f32x4*)(in + (size_t)i * 4);
    u16x4 o;
    o[0] = f2bf(v[0]); o[1] = f2bf(v[1]); o[2] = f2bf(v[2]); o[3] = f2bf(v[3]);
    *(u16x4*)(out + (size_t)i * 4) = o;
}

// ---------------- QKV GEMM: C[M=L,N=3E] = X[L,E] * Wattn^T, scatter epilogue ----------------
// 128x128 tile, BK=32, 4 waves (2x2). Staging via global_load_lds width=16 (m97 pattern).
__global__ __launch_bounds__(256, 2) void gemm_qkv(const unsigned short* __restrict__ A,
                                                   const unsigned short* __restrict__ B,
                                                   unsigned short* __restrict__ Qo,
                                                   unsigned short* __restrict__ Ko,
                                                   unsigned short* __restrict__ Vto) {
    __shared__ unsigned short As[128 * 32];
    __shared__ unsigned short Bs[128 * 32];
    const int tid = threadIdx.x;
    const int lane = tid & 63;
    const int wv = tid >> 6;
    const int wm = wv >> 1, wn = wv & 1;
    const int li = lane & 15, g = lane >> 4;
    const int m0 = blockIdx.y * 128, n0 = blockIdx.x * 128;
    f32x4 acc[4][4] = {};
    for (int k0 = 0; k0 < EMB; k0 += 32) {
        #pragma unroll
        for (int c = 0; c < 2; ++c) {
            const int o = c * 4096 + tid * 16;       // byte offset into 8KB tile
            const int r = o >> 6, cb = o & 63;
            gload16((const char*)A + ((size_t)(m0 + r) * EMB + k0) * 2 + cb, (char*)As + o);
            gload16((const char*)B + ((size_t)(n0 + r) * EMB + k0) * 2 + cb, (char*)Bs + o);
        }
        __syncthreads();
        u16x8 af[4], bfr[4];
        #pragma unroll
        for (int mb = 0; mb < 4; ++mb)
            af[mb] = *(const u16x8*)(As + (wm * 64 + mb * 16 + li) * 32 + g * 8);
        #pragma unroll
        for (int nb = 0; nb < 4; ++nb)
            bfr[nb] = *(const u16x8*)(Bs + (wn * 64 + nb * 16 + li) * 32 + g * 8);
        #pragma unroll
        for (int mb = 0; mb < 4; ++mb)
            #pragma unroll
            for (int nb = 0; nb < 4; ++nb)
                acc[mb][nb] = mfma16(af[mb], bfr[nb], acc[mb][nb]);
        __syncthreads();
    }
    for (int mb = 0; mb < 4; ++mb) {
        for (int nb = 0; nb < 4; ++nb) {
            for (int r = 0; r < 4; ++r) {
                const int m = m0 + wm * 64 + mb * 16 + g * 4 + r;
                const int n = n0 + wn * 64 + nb * 16 + li;
                const float v = acc[mb][nb][r];
                if (n < EMB) {
                    Qo[((size_t)(n >> 6) * LSEQ + m) * HD + (n & 63)] = f2bf(v * 0.125f);
                } else if (n < 2 * EMB) {
                    const int c = n - EMB;
                    Ko[((size_t)(c >> 6) * LSEQ + m) * HD + (c & 63)] = f2bf(v);
                } else {
                    const int c = n - 2 * EMB;
                    Vto[((size_t)(c >> 6) * HD + (c & 63)) * LSEQ + m] = f2bf(v);
                }
            }
        }
    }
}

// ---------------- flash attention (causal), swapped QK^T, paired q-tiles ----------------
// grid (32, 16): block handles q-tiles blockIdx.x and 63-blockIdx.x (65 KV tiles const).
// 4 waves x 16 q-rows. K/V double-buffered, 1 barrier per tile.
__global__ __launch_bounds__(256, 2) void attn_fwd(const unsigned short* __restrict__ Q,
                                                   const unsigned short* __restrict__ K,
                                                   const unsigned short* __restrict__ Vt,
                                                   unsigned short* __restrict__ Y) {
    __shared__ unsigned short Ks[2][64][72];
    __shared__ unsigned short Vs[2][64][72];   // V^T tile: [hd][kv]
    __shared__ unsigned short Ps[4][16][72];   // per-wave P[q_local][k]
    const int h = blockIdx.y;
    const int tid = threadIdx.x, lane = tid & 63, w = tid >> 6;
    const int g = lane >> 4, li = lane & 15;
    const int srow = tid >> 2, scol = (tid & 3) * 16;
    const unsigned short* Kh = K + (size_t)h * LSEQ * HD;
    const unsigned short* Vh = Vt + (size_t)h * HD * LSEQ;

    #pragma unroll 1
    for (int seg = 0; seg < 2; ++seg) {
        const int qt = seg ? (63 - (int)blockIdx.x) : (int)blockIdx.x;
        const int q0 = qt * 64;
        const int jmax = qt;
        const int qlane = q0 + w * 16 + li;
        const unsigned short* qrow = Q + ((size_t)h * LSEQ + qlane) * HD;
        const u16x8 bq0 = *(const u16x8*)(qrow + g * 8);
        const u16x8 bq1 = *(const u16x8*)(qrow + 32 + g * 8);
        float m_i = -1e30f, l_i = 0.f;
        f32x4 accO[4] = {};
        {   // prologue: stage tile 0 -> buf 0
            const unsigned short* kp = Kh + (size_t)srow * HD + scol;
            const unsigned short* vp = Vh + (size_t)srow * LSEQ + scol;
            u16x8 a0 = *(const u16x8*)kp, a1 = *(const u16x8*)(kp + 8);
            u16x8 b0 = *(const u16x8*)vp, b1 = *(const u16x8*)(vp + 8);
            *(u16x8*)&Ks[0][srow][scol] = a0; *(u16x8*)&Ks[0][srow][scol + 8] = a1;
            *(u16x8*)&Vs[0][srow][scol] = b0; *(u16x8*)&Vs[0][srow][scol + 8] = b1;
        }
        __syncthreads();
        for (int j = 0; j <= jmax; ++j) {
            const int cur = j & 1;
            const bool pf = (j < jmax);
            u16x8 kn0, kn1, vn0, vn1;
            if (pf) {   // async-stage split: issue next-tile loads early
                const unsigned short* kp = Kh + (size_t)(j + 1) * 64 * HD + (size_t)srow * HD + scol;
                const unsigned short* vp = Vh + (size_t)srow * LSEQ + (j + 1) * 64 + scol;
                kn0 = *(const u16x8*)kp; kn1 = *(const u16x8*)(kp + 8);
                vn0 = *(const u16x8*)vp; vn1 = *(const u16x8*)(vp + 8);
            }
            const int kbase = j * 64;
            if (kbase <= q0 + w * 16 + 15) {   // wave-uniform activity guard
                // QK^T swapped: S^T[k][q], lane holds 16 scores of q = qlane
                f32x4 s[4];
                #pragma unroll
                for (int jb = 0; jb < 4; ++jb) {
                    const u16x8 ka0 = *(const u16x8*)&Ks[cur][jb * 16 + li][g * 8];
                    const u16x8 ka1 = *(const u16x8*)&Ks[cur][jb * 16 + li][32 + g * 8];
                    f32x4 a = {};
                    a = mfma16(ka0, bq0, a);
                    a = mfma16(ka1, bq1, a);
                    s[jb] = a;
                }
                if (kbase + 63 > q0 + w * 16) {
                    #pragma unroll
                    for (int jb = 0; jb < 4; ++jb)
                        #pragma unroll
                        for (int r = 0; r < 4; ++r)
                            if (kbase + jb * 16 + g * 4 + r > qlane) s[jb][r] = -1e30f;
                }
                // in-register softmax: in-lane reduce + 2 shfls
                float mt = s[0][0];
                #pragma unroll
                for (int jb = 0; jb < 4; ++jb)
                    #pragma unroll
                    for (int r = 0; r < 4; ++r) mt = fmaxf(mt, s[jb][r]);
                mt = fmaxf(mt, __shfl_xor(mt, 16));
                mt = fmaxf(mt, __shfl_xor(mt, 32));
                const float mn = fmaxf(m_i, mt);
                const float al = __expf(m_i - mn);
                m_i = mn;
                float p[4][4], sum = 0.f;
                #pragma unroll
                for (int jb = 0; jb < 4; ++jb)
                    #pragma unroll
                    for (int r = 0; r < 4; ++r) {
                        p[jb][r] = __expf(s[jb][r] - mn);
                        sum += p[jb][r];
                    }
                sum += __shfl_xor(sum, 16);
                sum += __shfl_xor(sum, 32);
                l_i = l_i * al + sum;
                // pack P -> bf16, 4x ds_write_b64 (wave-private buffer)
                #pragma unroll
                for (int jb = 0; jb < 4; ++jb) {
                    uint2 pv;
                    pv.x = cvt_pk_bf16(p[jb][0], p[jb][1]);
                    pv.y = cvt_pk_bf16(p[jb][2], p[jb][3]);
                    *(uint2*)&Ps[w][li][jb * 16 + g * 4] = pv;
                }
                // deferred rescale (skip when running max unchanged)
                if (!__all(al == 1.0f)) {
                    float alq[4];
                    #pragma unroll
                    for (int r = 0; r < 4; ++r) alq[r] = __shfl(al, g * 4 + r);
                    #pragma unroll
                    for (int o = 0; o < 4; ++o)
                        #pragma unroll
                        for (int r = 0; r < 4; ++r) accO[o][r] *= alq[r];
                }
                asm volatile("s_waitcnt lgkmcnt(0)" ::: "memory");  // P write visible (same-wave RAW)
                const u16x8 ap0 = *(const u16x8*)&Ps[w][li][g * 8];
                const u16x8 ap1 = *(const u16x8*)&Ps[w][li][32 + g * 8];
                #pragma unroll
                for (int o = 0; o < 4; ++o) {
                    const u16x8 bv0 = *(const u16x8*)&Vs[cur][o * 16 + li][g * 8];
                    const u16x8 bv1 = *(const u16x8*)&Vs[cur][o * 16 + li][32 + g * 8];
                    accO[o] = mfma16(ap0, bv0, accO[o]);
                    accO[o] = mfma16(ap1, bv1, accO[o]);
                }
            }
            if (pf) {   // write prefetched tile to other buffer
                *(u16x8*)&Ks[cur ^ 1][srow][scol] = kn0; *(u16x8*)&Ks[cur ^ 1][srow][scol + 8] = kn1;
                *(u16x8*)&Vs[cur ^ 1][srow][scol] = vn0; *(u16x8*)&Vs[cur ^ 1][srow][scol + 8] = vn1;
            }
            __syncthreads();
        }
        float lq[4];
        #pragma unroll
        for (int r = 0; r < 4; ++r) lq[r] = __shfl(l_i, g * 4 + r);
        #pragma unroll
        for (int o = 0; o < 4; ++o)
            #pragma unroll
            for (int r = 0; r < 4; ++r) {
                const int row = q0 + w * 16 + g * 4 + r;
                Y[(size_t)row * EMB + h * HD + o * 16 + li] = f2bf(accO[o][r] / lq[r]);
            }
    }
}

// ---------------- proj GEMM: out[L,E] fp32 = Y[L,E] * Wproj^T ----------------
__global__ __launch_bounds__(256, 2) void gemm_proj(const unsigned short* __restrict__ A,
                                                    const unsigned short* __restrict__ B,
                                                    float* __restrict__ C) {
    __shared__ unsigned short As[128 * 32];
    __shared__ unsigned short Bs[128 * 32];
    const int tid = threadIdx.x;
    const int lane = tid & 63;
    const int wv = tid >> 6;
    const int wm = wv >> 1, wn = wv & 1;
    const int li = lane & 15, g = lane >> 4;
    const int m0 = blockIdx.y * 128, n0 = blockIdx.x * 128;
    f32x4 acc[4][4] = {};
    for (int k0 = 0; k0 < EMB; k0 += 32) {
        #pragma unroll
        for (int c = 0; c < 2; ++c) {
            const int o = c * 4096 + tid * 16;
            const int r = o >> 6, cb = o & 63;
            gload16((const char*)A + ((size_t)(m0 + r) * EMB + k0) * 2 + cb, (char*)As + o);
            gload16((const char*)B + ((size_t)(n0 + r) * EMB + k0) * 2 + cb, (char*)Bs + o);
        }
        __syncthreads();
        u16x8 af[4], bfr[4];
        #pragma unroll
        for (int mb = 0; mb < 4; ++mb)
            af[mb] = *(const u16x8*)(As + (wm * 64 + mb * 16 + li) * 32 + g * 8);
        #pragma unroll
        for (int nb = 0; nb < 4; ++nb)
            bfr[nb] = *(const u16x8*)(Bs + (wn * 64 + nb * 16 + li) * 32 + g * 8);
        #pragma unroll
        for (int mb = 0; mb < 4; ++mb)
            #pragma unroll
            for (int nb = 0; nb < 4; ++nb)
                acc[mb][nb] = mfma16(af[mb], bfr[nb], acc[mb][nb]);
        __syncthreads();
    }
    for (int mb = 0; mb < 4; ++mb)
        for (int nb = 0; nb < 4; ++nb)
            for (int r = 0; r < 4; ++r) {
                const int m = m0 + wm * 64 + mb * 16 + g * 4 + r;
                const int n = n0 + wn * 64 + nb * 16 + li;
                C[(size_t)m * EMB + n] = acc[mb][nb][r];
            }
}

extern "C" void kernel_launch(void* const* d_in, const int* in_sizes, int n_in,
                              void* d_out, int out_size, void* d_ws, size_t ws_size,
                              hipStream_t stream) {
    const float* x      = (const float*)d_in[0];
    const float* w_attn = (const float*)d_in[1];
    const float* w_proj = (const float*)d_in[2];
    float* out = (float*)d_out;

    unsigned short* ws  = (unsigned short*)d_ws;
    unsigned short* xb  = ws;                                  // L*E
    unsigned short* wab = xb + (size_t)LSEQ * EMB;             // 3E*E
    unsigned short* wpb = wab + (size_t)3 * EMB * EMB;         // E*E
    unsigned short* Qb  = wpb + (size_t)EMB * EMB;             // [H][L][64]
    unsigned short* Kb  = Qb + (size_t)LSEQ * EMB;
    unsigned short* Vtb = Kb + (size_t)LSEQ * EMB;             // [H][64][L]
    unsigned short* Yb  = Vtb + (size_t)LSEQ * EMB;            // L*E

    const int nx = LSEQ * EMB / 4, na = 3 * EMB * EMB / 4, np = EMB * EMB / 4;
    cvt_f32_bf16<<<(nx + 255) / 256, 256, 0, stream>>>(x, xb, nx);
    cvt_f32_bf16<<<(na + 255) / 256, 256, 0, stream>>>(w_attn, wab, na);
    cvt_f32_bf16<<<(np + 255) / 256, 256, 0, stream>>>(w_proj, wpb, np);

    gemm_qkv<<<dim3(3 * EMB / 128, LSEQ / 128), 256, 0, stream>>>(xb, wab, Qb, Kb, Vtb);
    attn_fwd<<<dim3(32, NH), 256, 0, stream>>>(Qb, Kb, Vtb, Yb);
    gemm_proj<<<dim3(EMB / 128, LSEQ / 128), 256, 0, stream>>>(Yb, wpb, out);
}

// Round 3
// 160.888 us; speedup vs baseline: 2.0429x; 1.0608x over previous
//
#include <hip/hip_runtime.h>

#define LSEQ 4096
#define EMB  1024
#define NH   16
#define HD   64

typedef __attribute__((ext_vector_type(8))) __bf16 bf16x8;
typedef __attribute__((ext_vector_type(4))) float f32x4;
typedef __attribute__((ext_vector_type(8))) unsigned short u16x8;
typedef __attribute__((ext_vector_type(4))) unsigned short u16x4;

// byte offset of 16B chunk `c` in row `r` of a [*][64]-short tile, XOR-swizzled
#define SWZ(r, c) (((r) * 128) + ((((c) ^ ((r) & 7))) << 4))

__device__ __forceinline__ unsigned short f2bf(float f) {
    union { float f; unsigned u; } v; v.f = f;
    unsigned r = v.u + 0x7fffu + ((v.u >> 16) & 1u);
    return (unsigned short)(r >> 16);
}

__device__ __forceinline__ unsigned cvt_pk_bf16(float a, float b) {
    unsigned r;
    asm("v_cvt_pk_bf16_f32 %0, %1, %2" : "=v"(r) : "v"(a), "v"(b));
    return r;
}

__device__ __forceinline__ f32x4 mfma16(u16x8 a, u16x8 b, f32x4 c) {
    return __builtin_amdgcn_mfma_f32_16x16x32_bf16(
        __builtin_bit_cast(bf16x8, a), __builtin_bit_cast(bf16x8, b), c, 0, 0, 0);
}

__device__ __forceinline__ void gload16(const void* g, void* l) {
    __builtin_amdgcn_global_load_lds((const __attribute__((address_space(1))) unsigned int*)g,
                                     (__attribute__((address_space(3))) unsigned int*)l,
                                     16, 0, 0);
}

// ---------------- fused fp32 -> bf16 convert (single launch, contiguous dest) ----------------
#define NX (LSEQ * EMB / 4)
#define NA (3 * EMB * EMB / 4)
#define NP (EMB * EMB / 4)
__global__ __launch_bounds__(256) void cvt_all(const float* __restrict__ x,
                                               const float* __restrict__ wa,
                                               const float* __restrict__ wp,
                                               unsigned short* __restrict__ out) {
    int i = blockIdx.x * 256 + threadIdx.x;
    if (i >= NX + NA + NP) return;
    const float* src;
    if (i < NX)            src = x + (size_t)i * 4;
    else if (i < NX + NA)  src = wa + (size_t)(i - NX) * 4;
    else                   src = wp + (size_t)(i - NX - NA) * 4;
    f32x4 v = *(const f32x4*)src;
    u16x4 o;
    o[0] = f2bf(v[0]); o[1] = f2bf(v[1]); o[2] = f2bf(v[2]); o[3] = f2bf(v[3]);
    *(u16x4*)(out + (size_t)i * 4) = o;
}

// ---------------- QKV GEMM: C[M=L,N=3E] = X[L,E] * Wattn^T, scatter epilogue ----------------
__global__ __launch_bounds__(256, 2) void gemm_qkv(const unsigned short* __restrict__ A,
                                                   const unsigned short* __restrict__ B,
                                                   unsigned short* __restrict__ Qo,
                                                   unsigned short* __restrict__ Ko,
                                                   unsigned short* __restrict__ Vto) {
    __shared__ unsigned short As[128 * 32];
    __shared__ unsigned short Bs[128 * 32];
    const int tid = threadIdx.x;
    const int lane = tid & 63;
    const int wv = tid >> 6;
    const int wm = wv >> 1, wn = wv & 1;
    const int li = lane & 15, g = lane >> 4;
    const int m0 = blockIdx.y * 128, n0 = blockIdx.x * 128;
    f32x4 acc[4][4] = {};
    for (int k0 = 0; k0 < EMB; k0 += 32) {
        #pragma unroll
        for (int c = 0; c < 2; ++c) {
            const int o = c * 4096 + tid * 16;
            const int r = o >> 6, cb = o & 63;
            gload16((const char*)A + ((size_t)(m0 + r) * EMB + k0) * 2 + cb, (char*)As + o);
            gload16((const char*)B + ((size_t)(n0 + r) * EMB + k0) * 2 + cb, (char*)Bs + o);
        }
        __syncthreads();
        u16x8 af[4], bfr[4];
        #pragma unroll
        for (int mb = 0; mb < 4; ++mb)
            af[mb] = *(const u16x8*)(As + (wm * 64 + mb * 16 + li) * 32 + g * 8);
        #pragma unroll
        for (int nb = 0; nb < 4; ++nb)
            bfr[nb] = *(const u16x8*)(Bs + (wn * 64 + nb * 16 + li) * 32 + g * 8);
        #pragma unroll
        for (int mb = 0; mb < 4; ++mb)
            #pragma unroll
            for (int nb = 0; nb < 4; ++nb)
                acc[mb][nb] = mfma16(af[mb], bfr[nb], acc[mb][nb]);
        __syncthreads();
    }
    for (int mb = 0; mb < 4; ++mb) {
        for (int nb = 0; nb < 4; ++nb) {
            for (int r = 0; r < 4; ++r) {
                const int m = m0 + wm * 64 + mb * 16 + g * 4 + r;
                const int n = n0 + wn * 64 + nb * 16 + li;
                const float v = acc[mb][nb][r];
                if (n < EMB) {
                    Qo[((size_t)(n >> 6) * LSEQ + m) * HD + (n & 63)] = f2bf(v * 0.125f);
                } else if (n < 2 * EMB) {
                    const int c = n - EMB;
                    Ko[((size_t)(c >> 6) * LSEQ + m) * HD + (c & 63)] = f2bf(v);
                } else {
                    const int c = n - 2 * EMB;
                    Vto[((size_t)(c >> 6) * HD + (c & 63)) * LSEQ + m] = f2bf(v);
                }
            }
        }
    }
}

// ---------------- flash attention (causal), swapped QK^T, paired q-tiles ----------------
__global__ __launch_bounds__(256, 2) void attn_fwd(const unsigned short* __restrict__ Q,
                                                   const unsigned short* __restrict__ K,
                                                   const unsigned short* __restrict__ Vt,
                                                   unsigned short* __restrict__ Y) {
    __shared__ unsigned short Ks[2][64][64];
    __shared__ unsigned short Vs[2][64][64];   // V^T tile: [hd][kv]
    __shared__ unsigned short Ps[4][16][64];   // per-wave P[q_local][k]
    const int h = blockIdx.y;
    const int tid = threadIdx.x, lane = tid & 63, w = tid >> 6;
    const int g = lane >> 4, li = lane & 15;
    const int srow = tid >> 2, scb = (tid & 3) * 2;
    char* KsB = (char*)Ks;
    char* VsB = (char*)Vs;
    char* PsB = (char*)Ps + w * 2048;
    const unsigned short* Kh = K + (size_t)h * LSEQ * HD;
    const unsigned short* Vh = Vt + (size_t)h * HD * LSEQ;

    #pragma unroll 1
    for (int seg = 0; seg < 2; ++seg) {
        const int qt = seg ? (63 - (int)blockIdx.x) : (int)blockIdx.x;
        const int q0 = qt * 64;
        const int jmax = qt;
        const int qlane = q0 + w * 16 + li;
        const unsigned short* qrow = Q + ((size_t)h * LSEQ + qlane) * HD;
        const u16x8 bq0 = *(const u16x8*)(qrow + g * 8);
        const u16x8 bq1 = *(const u16x8*)(qrow + 32 + g * 8);
        float m_i = -1e30f, l_i = 0.f;
        f32x4 accO[4] = {};
        {   // prologue: stage tile 0 -> buf 0
            const unsigned short* kp = Kh + (size_t)srow * HD + (tid & 3) * 16;
            const unsigned short* vp = Vh + (size_t)srow * LSEQ + (tid & 3) * 16;
            u16x8 a0 = *(const u16x8*)kp, a1 = *(const u16x8*)(kp + 8);
            u16x8 b0 = *(const u16x8*)vp, b1 = *(const u16x8*)(vp + 8);
            *(u16x8*)(KsB + SWZ(srow, scb))     = a0;
            *(u16x8*)(KsB + SWZ(srow, scb + 1)) = a1;
            *(u16x8*)(VsB + SWZ(srow, scb))     = b0;
            *(u16x8*)(VsB + SWZ(srow, scb + 1)) = b1;
        }
        __syncthreads();
        for (int j = 0; j <= jmax; ++j) {
            const int cur = j & 1;
            const int cbuf = cur * 8192;
            const bool pf = (j < jmax);
            u16x8 kn0, kn1, vn0, vn1;
            if (pf) {   // T14: issue next-tile global loads early
                const unsigned short* kp = Kh + (size_t)(j + 1) * 64 * HD + (size_t)srow * HD + (tid & 3) * 16;
                const unsigned short* vp = Vh + (size_t)srow * LSEQ + (j + 1) * 64 + (tid & 3) * 16;
                kn0 = *(const u16x8*)kp; kn1 = *(const u16x8*)(kp + 8);
                vn0 = *(const u16x8*)vp; vn1 = *(const u16x8*)(vp + 8);
            }
            const int kbase = j * 64;
            if (kbase <= q0 + w * 16 + 15) {
                u16x8 bv0[4], bv1[4];
                #pragma unroll
                for (int o = 0; o < 4; ++o) {
                    bv0[o] = *(const u16x8*)(VsB + cbuf + SWZ(o * 16 + li, g));
                    bv1[o] = *(const u16x8*)(VsB + cbuf + SWZ(o * 16 + li, 4 + g));
                }
                f32x4 s[4];
                __builtin_amdgcn_s_setprio(1);
                #pragma unroll
                for (int jb = 0; jb < 4; ++jb) {
                    const u16x8 ka0 = *(const u16x8*)(KsB + cbuf + SWZ(jb * 16 + li, g));
                    const u16x8 ka1 = *(const u16x8*)(KsB + cbuf + SWZ(jb * 16 + li, 4 + g));
                    f32x4 a = {};
                    a = mfma16(ka0, bq0, a);
                    a = mfma16(ka1, bq1, a);
                    s[jb] = a;
                }
                __builtin_amdgcn_s_setprio(0);
                if (kbase + 63 > q0 + w * 16) {
                    #pragma unroll
                    for (int jb = 0; jb < 4; ++jb)
                        #pragma unroll
                        for (int r = 0; r < 4; ++r)
                            if (kbase + jb * 16 + g * 4 + r > qlane) s[jb][r] = -1e30f;
                }
                float mt = s[0][0];
                #pragma unroll
                for (int jb = 0; jb < 4; ++jb)
                    #pragma unroll
                    for (int r = 0; r < 4; ++r) mt = fmaxf(mt, s[jb][r]);
                mt = fmaxf(mt, __shfl_xor(mt, 16));
                mt = fmaxf(mt, __shfl_xor(mt, 32));
                // T13 defer-max: only update max (and rescale) when growth > 8
                const bool need = !__all(mt - m_i <= 8.0f);
                float al = 1.0f;
                if (need) {
                    const float mn = fmaxf(m_i, mt);
                    al = __expf(m_i - mn);
                    m_i = mn;
                }
                float p[4][4], sum = 0.f;
                #pragma unroll
                for (int jb = 0; jb < 4; ++jb)
                    #pragma unroll
                    for (int r = 0; r < 4; ++r) {
                        p[jb][r] = __expf(s[jb][r] - m_i);
                        sum += p[jb][r];
                    }
                sum += __shfl_xor(sum, 16);
                sum += __shfl_xor(sum, 32);
                #pragma unroll
                for (int jb = 0; jb < 4; ++jb) {
                    uint2 pv;
                    pv.x = cvt_pk_bf16(p[jb][0], p[jb][1]);
                    pv.y = cvt_pk_bf16(p[jb][2], p[jb][3]);
                    *(uint2*)(PsB + SWZ(li, jb * 2 + (g >> 1)) + (g & 1) * 8) = pv;
                }
                l_i = l_i * al + sum;
                if (need) {
                    float alq[4];
                    #pragma unroll
                    for (int r = 0; r < 4; ++r) alq[r] = __shfl(al, g * 4 + r);
                    #pragma unroll
                    for (int o = 0; o < 4; ++o)
                        #pragma unroll
                        for (int r = 0; r < 4; ++r) accO[o][r] *= alq[r];
                }
                asm volatile("s_waitcnt lgkmcnt(0)" ::: "memory");
                __builtin_amdgcn_sched_barrier(0);
                const u16x8 ap0 = *(const u16x8*)(PsB + SWZ(li, g));
                const u16x8 ap1 = *(const u16x8*)(PsB + SWZ(li, 4 + g));
                __builtin_amdgcn_s_setprio(1);
                #pragma unroll
                for (int o = 0; o < 4; ++o) {
                    accO[o] = mfma16(ap0, bv0[o], accO[o]);
                    accO[o] = mfma16(ap1, bv1[o], accO[o]);
                }
                __builtin_amdgcn_s_setprio(0);
            }
            if (pf) {
                const int nb = (cur ^ 1) * 8192;
                *(u16x8*)(KsB + nb + SWZ(srow, scb))     = kn0;
                *(u16x8*)(KsB + nb + SWZ(srow, scb + 1)) = kn1;
                *(u16x8*)(VsB + nb + SWZ(srow, scb))     = vn0;
                *(u16x8*)(VsB + nb + SWZ(srow, scb + 1)) = vn1;
            }
            __syncthreads();
        }
        float lq[4];
        #pragma unroll
        for (int r = 0; r < 4; ++r) lq[r] = __shfl(l_i, g * 4 + r);
        #pragma unroll
        for (int o = 0; o < 4; ++o)
            #pragma unroll
            for (int r = 0; r < 4; ++r) {
                const int row = q0 + w * 16 + g * 4 + r;
                Y[(size_t)row * EMB + h * HD + o * 16 + li] = f2bf(accO[o][r] / lq[r]);
            }
    }
}

// ---------------- proj GEMM: out[L,E] fp32 = Y[L,E] * Wproj^T ----------------
__global__ __launch_bounds__(256, 2) void gemm_proj(const unsigned short* __restrict__ A,
                                                    const unsigned short* __restrict__ B,
                                                    float* __restrict__ C) {
    __shared__ unsigned short As[128 * 32];
    __shared__ unsigned short Bs[128 * 32];
    const int tid = threadIdx.x;
    const int lane = tid & 63;
    const int wv = tid >> 6;
    const int wm = wv >> 1, wn = wv & 1;
    const int li = lane & 15, g = lane >> 4;
    const int m0 = blockIdx.y * 128, n0 = blockIdx.x * 128;
    f32x4 acc[4][4] = {};
    for (int k0 = 0; k0 < EMB; k0 += 32) {
        #pragma unroll
        for (int c = 0; c < 2; ++c) {
            const int o = c * 4096 + tid * 16;
            const int r = o >> 6, cb = o & 63;
            gload16((const char*)A + ((size_t)(m0 + r) * EMB + k0) * 2 + cb, (char*)As + o);
            gload16((const char*)B + ((size_t)(n0 + r) * EMB + k0) * 2 + cb, (char*)Bs + o);
        }
        __syncthreads();
        u16x8 af[4], bfr[4];
        #pragma unroll
        for (int mb = 0; mb < 4; ++mb)
            af[mb] = *(const u16x8*)(As + (wm * 64 + mb * 16 + li) * 32 + g * 8);
        #pragma unroll
        for (int nb = 0; nb < 4; ++nb)
            bfr[nb] = *(const u16x8*)(Bs + (wn * 64 + nb * 16 + li) * 32 + g * 8);
        #pragma unroll
        for (int mb = 0; mb < 4; ++mb)
            #pragma unroll
            for (int nb = 0; nb < 4; ++nb)
                acc[mb][nb] = mfma16(af[mb], bfr[nb], acc[mb][nb]);
        __syncthreads();
    }
    for (int mb = 0; mb < 4; ++mb)
        for (int nb = 0; nb < 4; ++nb)
            for (int r = 0; r < 4; ++r) {
                const int m = m0 + wm * 64 + mb * 16 + g * 4 + r;
                const int n = n0 + wn * 64 + nb * 16 + li;
                C[(size_t)m * EMB + n] = acc[mb][nb][r];
            }
}

extern "C" void kernel_launch(void* const* d_in, const int* in_sizes, int n_in,
                              void* d_out, int out_size, void* d_ws, size_t ws_size,
                              hipStream_t stream) {
    const float* x      = (const float*)d_in[0];
    const float* w_attn = (const float*)d_in[1];
    const float* w_proj = (const float*)d_in[2];
    float* out = (float*)d_out;

    unsigned short* ws  = (unsigned short*)d_ws;
    unsigned short* xb  = ws;
    unsigned short* wab = xb + (size_t)LSEQ * EMB;
    unsigned short* wpb = wab + (size_t)3 * EMB * EMB;
    unsigned short* Qb  = wpb + (size_t)EMB * EMB;
    unsigned short* Kb  = Qb + (size_t)LSEQ * EMB;
    unsigned short* Vtb = Kb + (size_t)LSEQ * EMB;
    unsigned short* Yb  = Vtb + (size_t)LSEQ * EMB;

    const int ntot = NX + NA + NP;
    cvt_all<<<(ntot + 255) / 256, 256, 0, stream>>>(x, w_attn, w_proj, xb);
    gemm_qkv<<<dim3(3 * EMB / 128, LSEQ / 128), 256, 0, stream>>>(xb, wab, Qb, Kb, Vtb);
    attn_fwd<<<dim3(32, NH), 256, 0, stream>>>(Qb, Kb, Vtb, Yb);
    gemm_proj<<<dim3(EMB / 128, LSEQ / 128), 256, 0, stream>>>(Yb, wpb, out);
}